// Round 2
// baseline (89.187 us; speedup 1.0000x reference)
//
#include <hip/hip_runtime.h>

// Problem constants (match reference setup_inputs)
#define K_SIZE 5
#define PAD 2
#define SAMPLE_NUM 15
#define DEPTH_MAX 192.0f

constexpr int B = 2, C = 32, H = 240, W = 320;
constexpr int HW = H * W;

__global__ __launch_bounds__(256) void adaptive_sample_kernel(
    const float* __restrict__ depth,      // [B,1,H,W]
    const float* __restrict__ sn,         // [B,3,H,W]
    const float* __restrict__ features,   // [B,C,H,W]
    const float* __restrict__ guide,      // [B,H,W,25]
    const int*   __restrict__ sample_idx, // [15]
    float* __restrict__ out,              // [B,C,H,W]
    float* __restrict__ feat_out)         // [B,C,H,W]
{
    int n = blockIdx.x * blockDim.x + threadIdx.x;
    if (n >= B * HW) return;
    int b   = n / HW;
    int pix = n - b * HW;
    int y   = pix / W;
    int x   = pix - y * W;

    const float* snb = sn + (size_t)b * 3 * HW;
    const float* db  = depth + (size_t)b * HW;
    const float* gb  = guide + ((size_t)b * HW + pix) * (K_SIZE * K_SIZE);

    // center_n per reference: RAW RESHAPE of [B,3,H,W] to (B,H,W,3):
    // center_n[b,y,x,k] = sn_flat[b][y*W*3 + x*3 + k]
    int o = y * (W * 3) + x * 3;
    float cn0 = snb[o + 0];
    float cn1 = snb[o + 1];
    float cn2 = snb[o + 2];

    float w[SAMPLE_NUM];     // pre-softmax weights (0 for OOB / invalid depth)
    int   offs[SAMPLE_NUM];
    bool  inbv[SAMPLE_NUM];  // in-bounds -> feature contributes; OOB -> feat is 0 (zero pad)
    float m = 0.0f;          // all weights >= 0, so max >= 0

    #pragma unroll
    for (int s = 0; s < SAMPLE_NUM; ++s) {
        int p  = sample_idx[s];          // wave-uniform -> scalar load
        int dy = p / K_SIZE - PAD;
        int dx = p - (p / K_SIZE) * K_SIZE - PAD;
        int yy = y + dy, xx = x + dx;
        bool inb = (yy >= 0) && (yy < H) && (xx >= 0) && (xx < W);
        inbv[s] = inb;
        int noff = inb ? (yy * W + xx) : pix;  // clamp OOB (its accum weight is zeroed)
        offs[s] = noff;
        float ww = 0.0f;
        if (inb) {
            float d = db[noff];
            if (d > 0.0f && d < DEPTH_MAX) {
                float d0 = snb[noff]          - cn0;
                float d1 = snb[HW + noff]     - cn1;
                float d2 = snb[2 * HW + noff] - cn2;
                float diff = sqrtf(d0 * d0 + d1 * d1 + d2 * d2);
                ww = __expf(-0.5f * diff) * gb[p];
            }
        }
        w[s] = ww;
        m = fmaxf(m, ww);
    }

    // softmax over the 15 weights (zeros participate in the denominator)
    float sum = 0.0f;
    #pragma unroll
    for (int s = 0; s < SAMPLE_NUM; ++s) {
        w[s] = __expf(w[s] - m);
        sum += w[s];
    }
    float inv = 1.0f / sum;
    // accumulation weight: softmax prob, but OOB samples multiply a ZERO
    // feature (Unfold zero padding) -> zero their accumulation weight.
    #pragma unroll
    for (int s = 0; s < SAMPLE_NUM; ++s)
        w[s] = inbv[s] ? (w[s] * inv) : 0.0f;

    const float* fb  = features + (size_t)b * C * HW;
    float*       ob  = out      + (size_t)b * C * HW;
    float*       fob = feat_out + (size_t)b * C * HW;

    for (int c = 0; c < C; ++c) {
        const float* fc = fb + c * HW;
        float acc = 0.0f;
        #pragma unroll
        for (int s = 0; s < SAMPLE_NUM; ++s)
            acc += w[s] * fc[offs[s]];
        ob[c * HW + pix]  = acc;       // weighted sample output
        fob[c * HW + pix] = fc[pix];   // features passthrough (output 1)
    }
}

extern "C" void kernel_launch(void* const* d_in, const int* in_sizes, int n_in,
                              void* d_out, int out_size, void* d_ws, size_t ws_size,
                              hipStream_t stream) {
    const float* depth      = (const float*)d_in[0];
    const float* sn         = (const float*)d_in[1];
    const float* features   = (const float*)d_in[2];
    const float* guide      = (const float*)d_in[3];
    const int*   sample_idx = (const int*)d_in[4];

    float* out      = (float*)d_out;                      // [B,C,H,W]
    float* feat_out = (float*)d_out + (size_t)B * C * HW; // [B,C,H,W]

    int total = B * HW;
    int block = 256;
    int grid  = (total + block - 1) / block;
    adaptive_sample_kernel<<<grid, block, 0, stream>>>(
        depth, sn, features, guide, sample_idx, out, feat_out);
}

// Round 3
// 72.024 us; speedup vs baseline: 1.2383x; 1.2383x over previous
//
#include <hip/hip_runtime.h>

// Problem constants (match reference setup_inputs)
#define K_SIZE 5
#define PAD 2
#define SAMPLE_NUM 15
#define DEPTH_MAX 192.0f

constexpr int B = 2, C = 32, H = 240, W = 320;
constexpr int HW = H * W;
constexpr int NG  = 4;        // channel groups (threads per pixel)
constexpr int CPG = C / NG;   // 8 channels per thread
constexpr int PIX_BLOCKS = (B * HW) / 256;  // 600 (exact)

__global__ __launch_bounds__(256) void adaptive_sample_kernel(
    const float* __restrict__ depth,      // [B,1,H,W]
    const float* __restrict__ sn,         // [B,3,H,W]
    const float* __restrict__ features,   // [B,C,H,W]
    const float* __restrict__ guide,      // [B,H,W,25]
    const int*   __restrict__ sample_idx, // [15]
    float* __restrict__ out,              // [B,C,H,W]
    float* __restrict__ feat_out)         // [B,C,H,W]
{
    int pb = blockIdx.x % PIX_BLOCKS;     // pixel block
    int g  = blockIdx.x / PIX_BLOCKS;     // channel group
    int n  = pb * 256 + threadIdx.x;      // global pixel id in [0, B*HW)
    int b   = n / HW;
    int pix = n - b * HW;
    int y   = pix / W;
    int x   = pix - y * W;

    const float* snb = sn + (size_t)b * 3 * HW;
    const float* db  = depth + (size_t)b * HW;
    const float* gb  = guide + ((size_t)b * HW + pix) * (K_SIZE * K_SIZE);

    // center_n per reference: RAW RESHAPE of [B,3,H,W] to (B,H,W,3):
    // center_n[b,y,x,k] = sn_flat[b][y*W*3 + x*3 + k]
    int o = y * (W * 3) + x * 3;
    float cn0 = snb[o + 0];
    float cn1 = snb[o + 1];
    float cn2 = snb[o + 2];

    float w[SAMPLE_NUM];     // pre-softmax weights (0 for OOB / invalid depth)
    int   offs[SAMPLE_NUM];
    bool  inbv[SAMPLE_NUM];  // OOB -> feature is 0 (Unfold zero pad)
    float m = 0.0f;          // all weights >= 0

    #pragma unroll
    for (int s = 0; s < SAMPLE_NUM; ++s) {
        int p  = sample_idx[s];          // wave-uniform -> scalar load
        int dy = p / K_SIZE - PAD;
        int dx = p - (p / K_SIZE) * K_SIZE - PAD;
        int yy = y + dy, xx = x + dx;
        bool inb = (yy >= 0) && (yy < H) && (xx >= 0) && (xx < W);
        inbv[s] = inb;
        int noff = inb ? (yy * W + xx) : pix;  // clamped; accum weight zeroed below
        offs[s] = noff;
        float ww = 0.0f;
        if (inb) {
            float d = db[noff];
            if (d > 0.0f && d < DEPTH_MAX) {
                float d0 = snb[noff]          - cn0;
                float d1 = snb[HW + noff]     - cn1;
                float d2 = snb[2 * HW + noff] - cn2;
                float diff = sqrtf(d0 * d0 + d1 * d1 + d2 * d2);
                ww = __expf(-0.5f * diff) * gb[p];
            }
        }
        w[s] = ww;
        m = fmaxf(m, ww);
    }

    // softmax over the 15 weights (zeros participate in the denominator)
    float sum = 0.0f;
    #pragma unroll
    for (int s = 0; s < SAMPLE_NUM; ++s) {
        w[s] = __expf(w[s] - m);
        sum += w[s];
    }
    float inv = 1.0f / sum;
    // OOB samples multiply a ZERO feature -> zero their accumulation weight.
    #pragma unroll
    for (int s = 0; s < SAMPLE_NUM; ++s)
        w[s] = inbv[s] ? (w[s] * inv) : 0.0f;

    const float* fb  = features + (size_t)b * C * HW;
    float*       ob  = out      + (size_t)b * C * HW;
    float*       fob = feat_out + (size_t)b * C * HW;

    int c0 = g * CPG;
    #pragma unroll
    for (int cc = 0; cc < CPG; ++cc) {
        const float* fc = fb + (c0 + cc) * HW;
        float acc = 0.0f;
        #pragma unroll
        for (int s = 0; s < SAMPLE_NUM; ++s)
            acc += w[s] * fc[offs[s]];
        ob[(c0 + cc) * HW + pix]  = acc;       // weighted sample output
        fob[(c0 + cc) * HW + pix] = fc[pix];   // features passthrough (output 1)
    }
}

extern "C" void kernel_launch(void* const* d_in, const int* in_sizes, int n_in,
                              void* d_out, int out_size, void* d_ws, size_t ws_size,
                              hipStream_t stream) {
    const float* depth      = (const float*)d_in[0];
    const float* sn         = (const float*)d_in[1];
    const float* features   = (const float*)d_in[2];
    const float* guide      = (const float*)d_in[3];
    const int*   sample_idx = (const int*)d_in[4];

    float* out      = (float*)d_out;                      // [B,C,H,W]
    float* feat_out = (float*)d_out + (size_t)B * C * HW; // [B,C,H,W]

    int grid = PIX_BLOCKS * NG;  // 2400 blocks
    adaptive_sample_kernel<<<grid, 256, 0, stream>>>(
        depth, sn, features, guide, sample_idx, out, feat_out);
}